// Round 6
// baseline (1237.824 us; speedup 1.0000x reference)
//
#include <hip/hip_runtime.h>
#include <cstdint>
#include <cstddef>

// ---------------------------------------------------------------------------
// Problem constants
// ---------------------------------------------------------------------------
#define B_SZ 32
#define T_SZ 1024
#define DIN  80
#define H3   256   // encoder output dim
#define FEAT 768   // 3 * H3
#define G4   1024  // 4 * H (LSTM gates)
#define HH   256   // LSTM hidden

typedef __attribute__((ext_vector_type(8))) short short8;   // 8 x bf16 (4 VGPRs)
typedef __attribute__((ext_vector_type(4))) float f32x4;    // MFMA accumulator
typedef __attribute__((ext_vector_type(8))) int v8i;        // 32B fp8 fragment

__device__ inline float bf2f(unsigned short u) {
    return __uint_as_float(((unsigned int)u) << 16);
}
__device__ inline unsigned short f2bf(float f) {
    unsigned int u = __float_as_uint(f);
    u += 0x7fffu + ((u >> 16) & 1u);   // RNE
    return (unsigned short)(u >> 16);
}
// fast sigmoid/tanh: v_exp (exp2) + v_rcp
#define LOG2E 1.4426950408889634f
__device__ inline float sigm(float x) {
    return __builtin_amdgcn_rcpf(1.f + __builtin_amdgcn_exp2f(x * -LOG2E));
}
__device__ inline float tanh_f(float x) {
    return fmaf(2.f, __builtin_amdgcn_rcpf(1.f + __builtin_amdgcn_exp2f(x * (-2.f * LOG2E))), -1.f);
}

// async global->LDS, 16B per lane (dest must be linear: base + lane*16)
__device__ inline void gld16(const void* g, void* l) {
    __builtin_amdgcn_global_load_lds(
        (const __attribute__((address_space(1))) unsigned int*)g,
        (__attribute__((address_space(3))) unsigned int*)l, 16, 0, 0);
}

// ---------------------------------------------------------------------------
// fp32 -> bf16 conversion, float4-vectorized (n4 = n/4)
// ---------------------------------------------------------------------------
__device__ inline void cvt_seg(const float* __restrict__ s, unsigned short* __restrict__ d,
                               int n4, int i, int stride) {
    for (int k = i; k < n4; k += stride) {
        float4 f = ((const float4*)(const void*)s)[k];
        ushort4 u;
        u.x = f2bf(f.x); u.y = f2bf(f.y); u.z = f2bf(f.z); u.w = f2bf(f.w);
        ((ushort4*)(void*)d)[k] = u;
    }
}

// x + all five weight matrices + gate-bias sums + length argsort in ONE launch
__global__ void k_cvtw(const float* __restrict__ x,  unsigned short* __restrict__ xbf,
                       const float* __restrict__ s0, unsigned short* __restrict__ d0,
                       const float* __restrict__ s1, unsigned short* __restrict__ d1,
                       const float* __restrict__ s2, unsigned short* __restrict__ d2,
                       const float* __restrict__ s3, unsigned short* __restrict__ d3,
                       const float* __restrict__ s4, unsigned short* __restrict__ d4,
                       const float* __restrict__ bihf, const float* __restrict__ bhhf,
                       const float* __restrict__ bihb, const float* __restrict__ bhhb,
                       float* __restrict__ bsum,
                       const int* __restrict__ lens, int* __restrict__ order,
                       int* __restrict__ lens_sorted, float* __restrict__ out_order) {
    int i = blockIdx.x * 256 + threadIdx.x;
    int stride = gridDim.x * 256;
    cvt_seg(x,  xbf, 655360, i, stride);  // 32*1024*80 / 4
    cvt_seg(s0, d0, 10240,  i, stride);   // 512*80
    cvt_seg(s1, d1, 65536,  i, stride);   // 512*512
    cvt_seg(s2, d2, 32768,  i, stride);   // 256*512
    cvt_seg(s3, d3, 196608, i, stride);   // 1024*768
    cvt_seg(s4, d4, 196608, i, stride);   // 1024*768
    if (i < 2048)
        bsum[i] = (i < 1024) ? (bihf[i] + bhhf[i]) : (bihb[i - 1024] + bhhb[i - 1024]);
    if (i < B_SZ) {   // stable argsort by descending length (block 0 only)
        int lb = lens[i];
        int r = 0;
        for (int j = 0; j < B_SZ; ++j) {
            int lj = lens[j];
            if (lj > lb || (lj == lb && j < i)) ++r;
        }
        order[r] = i;
        lens_sorted[r] = lb;
        out_order[r] = (float)i;   // second tuple output, as float
    }
}

// zero the padded tail: out[bs, t, 0:512] = 0 for t >= len[bs]
__global__ void k_ztail(const int* __restrict__ lens_sorted, float* __restrict__ out) {
    int t = blockIdx.x, bs = blockIdx.y;
    if (t < lens_sorted[bs]) return;
    float4* p = (float4*)(out + ((size_t)bs * T_SZ + t) * 512);
    p[threadIdx.x] = make_float4(0.f, 0.f, 0.f, 0.f);   // 128 threads x 16B
}

// ---------------------------------------------------------------------------
// Whh [1024 rows (n), 256 cols (k)] fp32 -> fp8 e4m3 in MFMA B-fragment order
// for mfma_scale_f32_16x16x128_f8f6f4, IDENTITY n mapping (one col per lane):
//   slot (nt, kc): n = nt*16 + (lane&15), k = kc*128 + (lane>>4)*32 + j
// byte addr = ((nt*2 + kc)*64 + lane)*32. One thread per 16-byte half.
// Both directions in one launch: grid 128, dir = blockIdx.x >= 64.
// ---------------------------------------------------------------------------
__global__ void k_wfrag8(const float* __restrict__ Whhf, const float* __restrict__ Whhb,
                         unsigned char* __restrict__ dst) {
    int t = blockIdx.x * 256 + threadIdx.x;   // 0..32767
    int dir = t >> 14;
    t &= 16383;
    const float* Whh = dir ? Whhb : Whhf;
    unsigned char* d = dst + (size_t)dir * 262144;
    int lane = t & 63, hf = (t >> 6) & 1, kc = (t >> 7) & 1, nt = t >> 8;
    int n = nt * 16 + (lane & 15);
    int k0 = kc * 128 + (lane >> 4) * 32 + hf * 16;
    const float* p = Whh + (size_t)n * 256 + k0;
    unsigned int o[4];
    #pragma unroll
    for (int q = 0; q < 4; ++q) {
        float4 f = *(const float4*)(const void*)(p + 4 * q);
        o[q] = (__builtin_amdgcn_cvt_pk_fp8_f32(f.x, f.y, 0, false) & 0xffff)
             | (__builtin_amdgcn_cvt_pk_fp8_f32(f.z, f.w, 0, false) << 16);
    }
    int slot = (nt * 2 + kc) * 64 + lane;
    *(uint4*)(void*)(d + (size_t)slot * 32 + hf * 16) = make_uint4(o[0], o[1], o[2], o[3]);
}

// ---------------------------------------------------------------------------
// direct bf16 MFMA GEMM (kept only for K=80 encoder layer 0)
// Block tile 32(M) x 128(N), 4 waves (2x2), each wave 16x64 via 4 accums.
// ---------------------------------------------------------------------------
__global__ __launch_bounds__(256) void k_gemm(
    const unsigned short* __restrict__ A, const unsigned short* __restrict__ Bw,
    const float* __restrict__ bias,
    unsigned short* __restrict__ C, int M, int N, int K, int relu)
{
    int tid  = threadIdx.x;
    int lane = tid & 63;
    int wave = tid >> 6;
    int waveM = wave >> 1, waveN = wave & 1;
    int l16  = lane & 15;
    int quad = lane >> 4;
    int mBase = blockIdx.x * 32 + waveM * 16;
    int nBase = blockIdx.y * 128 + waveN * 64;

    const unsigned short* pA  = A  + (size_t)(mBase + l16) * K + quad * 8;
    const unsigned short* pB0 = Bw + (size_t)(nBase +  0 + l16) * K + quad * 8;
    const unsigned short* pB1 = Bw + (size_t)(nBase + 16 + l16) * K + quad * 8;
    const unsigned short* pB2 = Bw + (size_t)(nBase + 32 + l16) * K + quad * 8;
    const unsigned short* pB3 = Bw + (size_t)(nBase + 48 + l16) * K + quad * 8;

    const short8 z8 = {0, 0, 0, 0, 0, 0, 0, 0};
    f32x4 acc0 = {0.f, 0.f, 0.f, 0.f};
    f32x4 acc1 = acc0, acc2 = acc0, acc3 = acc0;

    for (int k0 = 0; k0 < K; k0 += 32) {
        bool ok = (k0 + quad * 8) < K;
        short8 av  = ok ? *(const short8*)(const void*)(pA  + k0) : z8;
        short8 bv0 = ok ? *(const short8*)(const void*)(pB0 + k0) : z8;
        short8 bv1 = ok ? *(const short8*)(const void*)(pB1 + k0) : z8;
        short8 bv2 = ok ? *(const short8*)(const void*)(pB2 + k0) : z8;
        short8 bv3 = ok ? *(const short8*)(const void*)(pB3 + k0) : z8;
        acc0 = __builtin_amdgcn_mfma_f32_16x16x32_bf16(av, bv0, acc0, 0, 0, 0);
        acc1 = __builtin_amdgcn_mfma_f32_16x16x32_bf16(av, bv1, acc1, 0, 0, 0);
        acc2 = __builtin_amdgcn_mfma_f32_16x16x32_bf16(av, bv2, acc2, 0, 0, 0);
        acc3 = __builtin_amdgcn_mfma_f32_16x16x32_bf16(av, bv3, acc3, 0, 0, 0);
    }

    int rowD = mBase + quad * 4;
    #pragma unroll
    for (int nt = 0; nt < 4; ++nt) {
        int col = nBase + nt * 16 + l16;
        float bsum = bias ? bias[col] : 0.f;
        f32x4 a = (nt == 0) ? acc0 : (nt == 1) ? acc1 : (nt == 2) ? acc2 : acc3;
        #pragma unroll
        for (int r = 0; r < 4; ++r) {
            float v = a[r] + bsum;
            if (relu) v = v > 0.f ? v : 0.f;
            C[(size_t)(rowD + r) * N + col] = f2bf(v);
        }
    }
}

// ---------------------------------------------------------------------------
// LDS-staged bf16 MFMA GEMM (m97 structure: 128x128 tile, BK=32,
// global_load_lds width 16, 2 barriers/K-step). K multiple of 32,
// M and N multiples of 128. grid = (N/128, M/128).
// C[M,N] = act(A[M,K] @ Bw[N,K]^T + bias), bf16 out, row stride ldc.
// Split-output mode (C2 != null): global cols >= 1024 go to C2 at col-1024.
// ---------------------------------------------------------------------------
__global__ __launch_bounds__(256) void k_gemm_t(
    const unsigned short* __restrict__ A, const unsigned short* __restrict__ Bw,
    const float* __restrict__ bias,
    unsigned short* __restrict__ C, unsigned short* __restrict__ C2,
    int N, int K, int ldc, int relu)
{
    __shared__ unsigned short lA[128 * 32];
    __shared__ unsigned short lB[128 * 32];
    int tid  = threadIdx.x;
    int lane = tid & 63;
    int wave = tid >> 6;
    int l16  = lane & 15, quad = lane >> 4;
    int wm = wave >> 1, wn = wave & 1;
    size_t mBase = (size_t)blockIdx.y * 128;
    size_t nBase = (size_t)blockIdx.x * 128;

    int c0 = tid, c1 = tid + 256;
    const unsigned short* sA0 = A  + (mBase + (c0 >> 2)) * K + (c0 & 3) * 8;
    const unsigned short* sA1 = A  + (mBase + (c1 >> 2)) * K + (c1 & 3) * 8;
    const unsigned short* sB0 = Bw + (nBase + (c0 >> 2)) * K + (c0 & 3) * 8;
    const unsigned short* sB1 = Bw + (nBase + (c1 >> 2)) * K + (c1 & 3) * 8;
    unsigned short* dA0 = lA + c0 * 8;
    unsigned short* dA1 = lA + c1 * 8;
    unsigned short* dB0 = lB + c0 * 8;
    unsigned short* dB1 = lB + c1 * 8;

    f32x4 acc[4][4];
    #pragma unroll
    for (int i = 0; i < 4; ++i)
        #pragma unroll
        for (int j = 0; j < 4; ++j) acc[i][j] = (f32x4){0.f, 0.f, 0.f, 0.f};

    const unsigned short* la = lA + (wm * 64 + l16) * 32 + quad * 8;
    const unsigned short* lb = lB + (wn * 64 + l16) * 32 + quad * 8;

    for (int k0 = 0; k0 < K; k0 += 32) {
        gld16(sA0 + k0, dA0);
        gld16(sA1 + k0, dA1);
        gld16(sB0 + k0, dB0);
        gld16(sB1 + k0, dB1);
        __syncthreads();                 // vmcnt(0) drain + barrier: tile ready
        short8 af[4], bf[4];
        #pragma unroll
        for (int i = 0; i < 4; ++i) {
            af[i] = *(const short8*)(const void*)(la + i * 16 * 32);
            bf[i] = *(const short8*)(const void*)(lb + i * 16 * 32);
        }
        #pragma unroll
        for (int i = 0; i < 4; ++i)
            #pragma unroll
            for (int j = 0; j < 4; ++j)
                acc[i][j] = __builtin_amdgcn_mfma_f32_16x16x32_bf16(af[i], bf[j], acc[i][j], 0, 0, 0);
        __syncthreads();                 // frags consumed before next overwrite
    }

    #pragma unroll
    for (int j = 0; j < 4; ++j) {
        int colg = (int)nBase + wn * 64 + j * 16 + l16;
        float bsum = bias[colg];
        unsigned short* dst = C;
        int cg = colg;
        if (C2 && colg >= 1024) { dst = C2; cg = colg - 1024; }
        #pragma unroll
        for (int i = 0; i < 4; ++i) {
            int row = (int)mBase + wm * 64 + i * 16 + quad * 4;
            #pragma unroll
            for (int r = 0; r < 4; ++r) {
                float v = acc[i][j][r] + bsum;
                if (relu) v = v > 0.f ? v : 0.f;
                dst[(size_t)(row + r) * ldc + cg] = f2bf(v);
            }
        }
    }
}

// ---------------------------------------------------------------------------
// delta features + batch reorder (unchanged)
// ---------------------------------------------------------------------------
__global__ void k_deltas(const unsigned short* __restrict__ hbuf, const int* __restrict__ order,
                         unsigned short* __restrict__ feat)
{
    int bt = blockIdx.x;        // bs*1024 + t
    int c  = threadIdx.x;       // 0..255
    int bs = bt >> 10, t = bt & 1023;
    int b  = order[bs];
    const unsigned short* hb = hbuf + (size_t)b * T_SZ * H3 + c;

    float hv[9];
    #pragma unroll
    for (int d = -4; d <= 4; ++d) {
        int tt = t + d;
        tt = tt < 0 ? 0 : (tt > T_SZ - 1 ? T_SZ - 1 : tt);
        hv[d + 4] = bf2f(hb[(size_t)tt * H3]);
    }
    float d1v[5];
    #pragma unroll
    for (int s = -2; s <= 2; ++s) {
        d1v[s + 2] = (hv[s + 5] - hv[s + 3]) * 0.5f + (hv[s + 6] - hv[s + 2]) * 0.25f;
    }
    int sp1 = (t + 1 > T_SZ - 1 ? T_SZ - 1 : t + 1) - t;
    int sm1 = (t - 1 < 0 ? 0 : t - 1) - t;
    int sp2 = (t + 2 > T_SZ - 1 ? T_SZ - 1 : t + 2) - t;
    int sm2 = (t - 2 < 0 ? 0 : t - 2) - t;
    float d2 = (d1v[2 + sp1] - d1v[2 + sm1]) * 0.5f + (d1v[2 + sp2] - d1v[2 + sm2]) * 0.25f;

    size_t fb = (size_t)bt * FEAT;
    feat[fb + c]       = hb[(size_t)t * H3];
    feat[fb + 256 + c] = f2bf(d1v[2]);
    feat[fb + 512 + c] = f2bf(d2);
}

// ---------------------------------------------------------------------------
// fp8 MX-MFMA LSTM recurrence v10: grid (rq 0..7, dir 0..1) = 16 blocks,
// 1024 threads (16 waves). Changes vs v9 (neutral at 824 us; the one
// counter that moved with structure was SQ_LDS_BANK_CONFLICT, ~220
// cyc/block-step on the serial ds_read path):
//  - hA layout changed from 32B-stride chunks (half of every 128B LDS row
//    unused per read cycle -> counted as conflicts) to the canonical
//    16B-stride contiguous pattern: two 1KB half-planes per K-chunk,
//      byte(m,k) at kc*2048 + ((k>>4)&1)*1024 + (((k&127)>>5)*16 + m)*16 + (k&15)
//    Lane reads 4x ds_read_b128 at {0,1024,2048,3072} + lane*16 -- all
//    contiguous across the wave, conflict-free.
//  - s_setprio(1/0) around the MFMA cluster (waves desync across steps;
//    this is the regime where setprio measured positive).
// ---------------------------------------------------------------------------
__global__ __launch_bounds__(1024, 4) void k_lstm_fp8(
    const unsigned short* __restrict__ g3f, const unsigned short* __restrict__ g3b,
    const unsigned char* __restrict__ wfrag8,
    const float* __restrict__ h0, const float* __restrict__ c0,
    const int* __restrict__ lens_sorted, float* __restrict__ out)
{
    int rq = blockIdx.x, dir = blockIdx.y;
    const unsigned short* g3 = (dir ? g3b : g3f) + (size_t)rq * 4194304;
    const unsigned char* wsrc = wfrag8 + (size_t)dir * 262144;

    __shared__ __align__(16) unsigned char hA[2][4096];

    int tid = threadIdx.x;
    int w = tid >> 6, lane = tid & 63;
    int l16 = lane & 15, quad = lane >> 4;

    // Whh fragments for this wave's 16 columns: regB[gb][kc], nt = gb*16 + w
    v8i regB[4][2];
    #pragma unroll
    for (int gb = 0; gb < 4; ++gb)
        #pragma unroll
        for (int kc = 0; kc < 2; ++kc) {
            int nt = gb * 16 + w;
            regB[gb][kc] = *(const v8i*)(const void*)
                (wsrc + ((size_t)((nt * 2 + kc) * 64 + lane)) * 32);
        }

    // zero both hA buffers (m-rows != 4b stay zero forever; fp8 0x00 == 0.0)
    for (int i = tid; i < 2048; i += 1024) ((unsigned int*)(void*)hA)[i] = 0;
    __syncthreads();
    // h0 -> hA[0] at m-row 4b, new contiguous half-plane layout
    {
        int b = tid >> 8, c = tid & 255;
        float hv = h0[(size_t)dir * B_SZ * HH + (size_t)(rq * 4 + b) * HH + c];
        int adr = (c >> 7) * 2048 + ((c >> 4) & 1) * 1024
                + (((c & 127) >> 5) * 16 + 4 * b) * 16 + (c & 15);
        hA[0][adr] =
            (unsigned char)(__builtin_amdgcn_cvt_pk_fp8_f32(hv, hv, 0, false) & 0xff);
    }

    int grow = rq * 4 + quad;            // this lane's batch row (batch = quad)
    int elen = lens_sorted[grow];
    int maxlen = lens_sorted[rq * 4];    // sorted desc -> first of quad is max
    int col = w * 16 + l16;              // this lane's single h column
    float c2 = c0[(size_t)dir * B_SZ * HH + (size_t)grow * HH + col];
    float* out_r = out + (size_t)grow * T_SZ * 512 + dir * HH + col;
    // gates row-major [row = bs*1024 + t][1024]; this lane's column
    const unsigned short* gb0 = g3 + ((size_t)quad << 20) + col;
    // LDS write offset for this lane's fp8 h byte at m-row 4*quad (new layout)
    int woff = (col >> 7) * 2048 + ((col >> 4) & 1) * 1024
             + (((col & 127) >> 5) * 16 + 4 * quad) * 16 + (col & 15);

    // prefetch step-0 gate inputs (4 ushorts: one per gate, 512B apart)
    int tr0 = dir ? (elen - 1) : 0;
    const unsigned short* rp = gb0 + ((size_t)tr0 << 10);
    unsigned short gI = rp[0], gF = rp[256], gG = rp[512], gO = rp[768];
    __syncthreads();

    for (int s = 0; s < maxlen; ++s) {
        // A-fragments FIRST: 4 contiguous-pattern b128 reads (conflict-free)
        const unsigned char* Ab = hA[s & 1];
        uint4 q0 = *(const uint4*)(const void*)(Ab + lane * 16);
        uint4 q1 = *(const uint4*)(const void*)(Ab + 1024 + lane * 16);
        uint4 q2 = *(const uint4*)(const void*)(Ab + 2048 + lane * 16);
        uint4 q3 = *(const uint4*)(const void*)(Ab + 3072 + lane * 16);
        v8i a0 = (v8i){(int)q0.x, (int)q0.y, (int)q0.z, (int)q0.w,
                       (int)q1.x, (int)q1.y, (int)q1.z, (int)q1.w};
        v8i a1 = (v8i){(int)q2.x, (int)q2.y, (int)q2.z, (int)q2.w,
                       (int)q3.x, (int)q3.y, (int)q3.z, (int)q3.w};

        // prefetch NEXT step's gates (lands during this step's MFMAs)
        int trn = dir ? (elen - 2 - s) : (s + 1);
        trn = trn < 0 ? 0 : (trn > T_SZ - 1 ? T_SZ - 1 : trn);
        const unsigned short* rn = gb0 + ((size_t)trn << 10);
        unsigned short nI = rn[0], nF = rn[256], nG = rn[512], nO = rn[768];

        // gate input enters as the C-operand (element 0 = row 4*quad = batch)
        f32x4 acc[4];
        acc[0] = (f32x4){bf2f(gI), 0.f, 0.f, 0.f};
        acc[1] = (f32x4){bf2f(gF), 0.f, 0.f, 0.f};
        acc[2] = (f32x4){bf2f(gG), 0.f, 0.f, 0.f};
        acc[3] = (f32x4){bf2f(gO), 0.f, 0.f, 0.f};
        __builtin_amdgcn_s_setprio(1);
        #pragma unroll
        for (int gb = 0; gb < 4; ++gb)
            acc[gb] = __builtin_amdgcn_mfma_scale_f32_16x16x128_f8f6f4(
                a0, regB[gb][0], acc[gb], 0, 0, 0, 0x7F7F7F7F, 0, 0x7F7F7F7F);
        #pragma unroll
        for (int gb = 0; gb < 4; ++gb)   // o gate (gb=3) last
            acc[gb] = __builtin_amdgcn_mfma_scale_f32_16x16x128_f8f6f4(
                a1, regB[gb][1], acc[gb], 0, 0, 0, 0x7F7F7F7F, 0, 0x7F7F7F7F);
        __builtin_amdgcn_s_setprio(0);

        // epilogue: ONE h value per lane
        c2 = sigm(acc[1][0]) * c2 + sigm(acc[0][0]) * tanh_f(acc[2][0]);
        float tc = tanh_f(c2);
        float hv = sigm(acc[3][0]) * tc;

        hA[(s + 1) & 1][woff] =
            (unsigned char)(__builtin_amdgcn_cvt_pk_fp8_f32(hv, hv, 0, false) & 0xff);
        if (s < elen) {
            int t_out = dir ? (elen - 1 - s) : s;
            out_r[(size_t)t_out * 512] = hv;
        }
        gI = nI; gF = nF; gG = nG; gO = nO;
        // raw barrier: only the LDS h-write must drain; the out-store and
        // next-step gate loads stay in flight across the barrier.
        asm volatile("s_waitcnt lgkmcnt(0)" ::: "memory");
        __builtin_amdgcn_s_barrier();
    }
}

// ---------------------------------------------------------------------------
// Workspace layout (bytes). gates_f overlaps dead a0/a1 regions.
// ---------------------------------------------------------------------------
#define OFF_XBF    ((size_t)0)
#define OFF_A0     ((size_t)5242880)
#define OFF_A1     ((size_t)38797312)
#define OFF_HBUF   ((size_t)72351744)
#define OFF_FEAT   ((size_t)89128960)
#define OFF_GF     OFF_A0                  /* 67,108,864 B over a0+a1 (dead) */
#define OFF_GB     ((size_t)139460608)
#define OFF_W0     ((size_t)206569472)
#define OFF_W1     ((size_t)206651392)
#define OFF_W2     ((size_t)207175680)
#define OFF_WIHF   ((size_t)207437824)
#define OFF_WIHB   ((size_t)209010688)     /* contiguous after WIHF (merged B) */
#define OFF_WFRAG  ((size_t)210583552)     /* 524288 B: fp8 Whh fragments f+b */
#define OFF_BSUM   ((size_t)211107840)     /* float[2048] gate bias sums */
#define OFF_ORDER  ((size_t)212680704)
#define OFF_LENS   ((size_t)212680832)

extern "C" void kernel_launch(void* const* d_in, const int* in_sizes, int n_in,
                              void* d_out, int out_size, void* d_ws, size_t ws_size,
                              hipStream_t stream)
{
    const float* x    = (const float*)d_in[0];
    const int*   xlen = (const int*)d_in[1];
    const float* eW0  = (const float*)d_in[2];
    const float* eb0  = (const float*)d_in[3];
    const float* eW1  = (const float*)d_in[4];
    const float* eb1  = (const float*)d_in[5];
    const float* eW2  = (const float*)d_in[6];
    const float* eb2  = (const float*)d_in[7];
    const float* Wihf = (const float*)d_in[8];
    const float* Whhf = (const float*)d_in[9];
    const float* bihf = (const float*)d_in[10];
    const float* bhhf = (const float*)d_in[11];
    const float* Wihb = (const float*)d_in[12];
    const float* Whhb = (const float*)d_in[13];
    const float* bihb = (const float*)d_in[14];
    const float* bhhb = (const float*)d_in[15];
    const float* h0   = (const float*)d_in[16];
    const float* c0   = (const float*)d_in[17];
    float* out = (float*)d_out;

    char* ws = (char*)d_ws;
    unsigned short* xbf    = (unsigned short*)(ws + OFF_XBF);
    unsigned short* a0     = (unsigned short*)(ws + OFF_A0);
    unsigned short* a1     = (unsigned short*)(ws + OFF_A1);
    unsigned short* hbuf   = (unsigned short*)(ws + OFF_HBUF);
    unsigned short* feat   = (unsigned short*)(ws + OFF_FEAT);
    unsigned short* gatesF = (unsigned short*)(ws + OFF_GF);
    unsigned short* gatesB = (unsigned short*)(ws + OFF_GB);
    unsigned short* w0     = (unsigned short*)(ws + OFF_W0);
    unsigned short* w1     = (unsigned short*)(ws + OFF_W1);
    unsigned short* w2     = (unsigned short*)(ws + OFF_W2);
    unsigned short* wihf   = (unsigned short*)(ws + OFF_WIHF);
    unsigned short* wihb   = (unsigned short*)(ws + OFF_WIHB);
    unsigned char*  wfrag8 = (unsigned char*)(ws + OFF_WFRAG);
    float* bsum            = (float*)(ws + OFF_BSUM);
    int* order             = (int*)(ws + OFF_ORDER);
    int* lens_sorted       = (int*)(ws + OFF_LENS);

    // prep: all conversions + bias sums + argsort in two launches
    k_cvtw<<<1024, 256, 0, stream>>>(x, xbf, eW0, w0, eW1, w1, eW2, w2,
                                     Wihf, wihf, Wihb, wihb,
                                     bihf, bhhf, bihb, bhhb, bsum,
                                     xlen, order, lens_sorted,
                                     out + (size_t)B_SZ * T_SZ * 512);
    k_wfrag8<<<128, 256, 0, stream>>>(Whhf, Whhb, wfrag8);
    k_ztail<<<dim3(T_SZ, B_SZ), 128, 0, stream>>>(lens_sorted, out);

    // encoder: 80 -> 512 -> 512 -> 256, ReLU each layer (row-major stores)
    k_gemm<<<dim3(1024, 4), 256, 0, stream>>>(xbf, w0, eb0, a0, 32768, 512, 80, 1);
    k_gemm_t<<<dim3(4, 256), 256, 0, stream>>>(a0, w1, eb1, a1,   nullptr, 512, 512, 512, 1);
    k_gemm_t<<<dim3(2, 256), 256, 0, stream>>>(a1, w2, eb2, hbuf, nullptr, 256, 512, 256, 1);

    // delta features + sort reorder -> feat[bs,t,768]
    k_deltas<<<32768, 256, 0, stream>>>(hbuf, order, feat);

    // gate inputs, BOTH directions in one GEMM: B = [wihf; wihb] (adjacent in
    // ws), cols < 1024 -> gatesF, >= 1024 -> gatesB (each [32768][1024]).
    k_gemm_t<<<dim3(16, 256), 256, 0, stream>>>(feat, wihf, bsum, gatesF, gatesB,
                                                2048, 768, 1024, 0);

    // fp8 MX recurrence: 16 independent blocks (2 dirs x 8 batch quads), no sync
    k_lstm_fp8<<<dim3(8, 2), 1024, 0, stream>>>(gatesF, gatesB, wfrag8, h0, c0,
                                                lens_sorted, out);
}

// Round 7
// 1131.198 us; speedup vs baseline: 1.0943x; 1.0943x over previous
//
#include <hip/hip_runtime.h>
#include <cstdint>
#include <cstddef>

// ---------------------------------------------------------------------------
// Problem constants
// ---------------------------------------------------------------------------
#define B_SZ 32
#define T_SZ 1024
#define DIN  80
#define H3   256   // encoder output dim
#define FEAT 768   // 3 * H3
#define G4   1024  // 4 * H (LSTM gates)
#define HH   256   // LSTM hidden

typedef __attribute__((ext_vector_type(8))) short short8;   // 8 x bf16 (4 VGPRs)
typedef __attribute__((ext_vector_type(4))) float f32x4;    // MFMA accumulator
typedef __attribute__((ext_vector_type(8))) int v8i;        // 32B fp8 fragment

__device__ inline float bf2f(unsigned short u) {
    return __uint_as_float(((unsigned int)u) << 16);
}
__device__ inline unsigned short f2bf(float f) {
    unsigned int u = __float_as_uint(f);
    u += 0x7fffu + ((u >> 16) & 1u);   // RNE
    return (unsigned short)(u >> 16);
}
// fast sigmoid/tanh: v_exp (exp2) + v_rcp
#define LOG2E 1.4426950408889634f
__device__ inline float sigm(float x) {
    return __builtin_amdgcn_rcpf(1.f + __builtin_amdgcn_exp2f(x * -LOG2E));
}
__device__ inline float tanh_f(float x) {
    return fmaf(2.f, __builtin_amdgcn_rcpf(1.f + __builtin_amdgcn_exp2f(x * (-2.f * LOG2E))), -1.f);
}

// async global->LDS, 16B per lane (dest must be linear: base + lane*16)
__device__ inline void gld16(const void* g, void* l) {
    __builtin_amdgcn_global_load_lds(
        (const __attribute__((address_space(1))) unsigned int*)g,
        (__attribute__((address_space(3))) unsigned int*)l, 16, 0, 0);
}

// ---------------------------------------------------------------------------
// fp32 -> bf16 conversion, float4-vectorized (n4 = n/4)
// ---------------------------------------------------------------------------
__device__ inline void cvt_seg(const float* __restrict__ s, unsigned short* __restrict__ d,
                               int n4, int i, int stride) {
    for (int k = i; k < n4; k += stride) {
        float4 f = ((const float4*)(const void*)s)[k];
        ushort4 u;
        u.x = f2bf(f.x); u.y = f2bf(f.y); u.z = f2bf(f.z); u.w = f2bf(f.w);
        ((ushort4*)(void*)d)[k] = u;
    }
}

// x + five weight matrices + gate-bias sums + argsort + Whh fp8 fragments,
// all in ONE launch (k_wfrag8 fused in: independent of the other segments).
__global__ void k_cvtw(const float* __restrict__ x,  unsigned short* __restrict__ xbf,
                       const float* __restrict__ s0, unsigned short* __restrict__ d0,
                       const float* __restrict__ s1, unsigned short* __restrict__ d1,
                       const float* __restrict__ s2, unsigned short* __restrict__ d2,
                       const float* __restrict__ s3, unsigned short* __restrict__ d3,
                       const float* __restrict__ s4, unsigned short* __restrict__ d4,
                       const float* __restrict__ bihf, const float* __restrict__ bhhf,
                       const float* __restrict__ bihb, const float* __restrict__ bhhb,
                       float* __restrict__ bsum,
                       const int* __restrict__ lens, int* __restrict__ order,
                       int* __restrict__ lens_sorted, float* __restrict__ out_order,
                       const float* __restrict__ Whhf, const float* __restrict__ Whhb,
                       unsigned char* __restrict__ wfrag) {
    int i = blockIdx.x * 256 + threadIdx.x;
    int stride = gridDim.x * 256;
    cvt_seg(x,  xbf, 655360, i, stride);  // 32*1024*80 / 4
    cvt_seg(s0, d0, 10240,  i, stride);   // 512*80
    cvt_seg(s1, d1, 65536,  i, stride);   // 512*512
    cvt_seg(s2, d2, 32768,  i, stride);   // 256*512
    cvt_seg(s3, d3, 196608, i, stride);   // 1024*768
    cvt_seg(s4, d4, 196608, i, stride);   // 1024*768
    if (i < 2048)
        bsum[i] = (i < 1024) ? (bihf[i] + bhhf[i]) : (bihb[i - 1024] + bhhb[i - 1024]);
    if (i < B_SZ) {   // stable argsort by descending length
        int lb = lens[i];
        int r = 0;
        for (int j = 0; j < B_SZ; ++j) {
            int lj = lens[j];
            if (lj > lb || (lj == lb && j < i)) ++r;
        }
        order[r] = i;
        lens_sorted[r] = lb;
        out_order[r] = (float)i;   // second tuple output, as float
    }
    // Whh -> fp8 MFMA B-fragments (identity n mapping, one col per lane):
    // slot (nt,kc): n = nt*16 + (lane&15), k = kc*128 + (lane>>4)*32 + j.
    // byte addr = ((nt*2+kc)*64 + lane)*32, one thread per 16B half.
    if (i < 32768) {
        int t = i;
        int dir = t >> 14;
        t &= 16383;
        const float* Whh = dir ? Whhb : Whhf;
        unsigned char* d = wfrag + (size_t)dir * 262144;
        int lane = t & 63, hf = (t >> 6) & 1, kc = (t >> 7) & 1, nt = t >> 8;
        int n = nt * 16 + (lane & 15);
        int k0 = kc * 128 + (lane >> 4) * 32 + hf * 16;
        const float* p = Whh + (size_t)n * 256 + k0;
        unsigned int o[4];
        #pragma unroll
        for (int q = 0; q < 4; ++q) {
            float4 f = *(const float4*)(const void*)(p + 4 * q);
            o[q] = (__builtin_amdgcn_cvt_pk_fp8_f32(f.x, f.y, 0, false) & 0xffff)
                 | (__builtin_amdgcn_cvt_pk_fp8_f32(f.z, f.w, 0, false) << 16);
        }
        int slot = (nt * 2 + kc) * 64 + lane;
        *(uint4*)(void*)(d + (size_t)slot * 32 + hf * 16) = make_uint4(o[0], o[1], o[2], o[3]);
    }
}

// zero the padded tail: out[bs, t, 0:512] = 0 for t >= len[bs]
__global__ void k_ztail(const int* __restrict__ lens_sorted, float* __restrict__ out) {
    int t = blockIdx.x, bs = blockIdx.y;
    if (t < lens_sorted[bs]) return;
    float4* p = (float4*)(out + ((size_t)bs * T_SZ + t) * 512);
    p[threadIdx.x] = make_float4(0.f, 0.f, 0.f, 0.f);   // 128 threads x 16B
}

// ---------------------------------------------------------------------------
// direct bf16 MFMA GEMM (kept only for K=80 encoder layer 0)
// Block tile 32(M) x 128(N), 4 waves (2x2), each wave 16x64 via 4 accums.
// ---------------------------------------------------------------------------
__global__ __launch_bounds__(256) void k_gemm(
    const unsigned short* __restrict__ A, const unsigned short* __restrict__ Bw,
    const float* __restrict__ bias,
    unsigned short* __restrict__ C, int M, int N, int K, int relu)
{
    int tid  = threadIdx.x;
    int lane = tid & 63;
    int wave = tid >> 6;
    int waveM = wave >> 1, waveN = wave & 1;
    int l16  = lane & 15;
    int quad = lane >> 4;
    int mBase = blockIdx.x * 32 + waveM * 16;
    int nBase = blockIdx.y * 128 + waveN * 64;

    const unsigned short* pA  = A  + (size_t)(mBase + l16) * K + quad * 8;
    const unsigned short* pB0 = Bw + (size_t)(nBase +  0 + l16) * K + quad * 8;
    const unsigned short* pB1 = Bw + (size_t)(nBase + 16 + l16) * K + quad * 8;
    const unsigned short* pB2 = Bw + (size_t)(nBase + 32 + l16) * K + quad * 8;
    const unsigned short* pB3 = Bw + (size_t)(nBase + 48 + l16) * K + quad * 8;

    const short8 z8 = {0, 0, 0, 0, 0, 0, 0, 0};
    f32x4 acc0 = {0.f, 0.f, 0.f, 0.f};
    f32x4 acc1 = acc0, acc2 = acc0, acc3 = acc0;

    for (int k0 = 0; k0 < K; k0 += 32) {
        bool ok = (k0 + quad * 8) < K;
        short8 av  = ok ? *(const short8*)(const void*)(pA  + k0) : z8;
        short8 bv0 = ok ? *(const short8*)(const void*)(pB0 + k0) : z8;
        short8 bv1 = ok ? *(const short8*)(const void*)(pB1 + k0) : z8;
        short8 bv2 = ok ? *(const short8*)(const void*)(pB2 + k0) : z8;
        short8 bv3 = ok ? *(const short8*)(const void*)(pB3 + k0) : z8;
        acc0 = __builtin_amdgcn_mfma_f32_16x16x32_bf16(av, bv0, acc0, 0, 0, 0);
        acc1 = __builtin_amdgcn_mfma_f32_16x16x32_bf16(av, bv1, acc1, 0, 0, 0);
        acc2 = __builtin_amdgcn_mfma_f32_16x16x32_bf16(av, bv2, acc2, 0, 0, 0);
        acc3 = __builtin_amdgcn_mfma_f32_16x16x32_bf16(av, bv3, acc3, 0, 0, 0);
    }

    int rowD = mBase + quad * 4;
    #pragma unroll
    for (int nt = 0; nt < 4; ++nt) {
        int col = nBase + nt * 16 + l16;
        float bsum = bias ? bias[col] : 0.f;
        f32x4 a = (nt == 0) ? acc0 : (nt == 1) ? acc1 : (nt == 2) ? acc2 : acc3;
        #pragma unroll
        for (int r = 0; r < 4; ++r) {
            float v = a[r] + bsum;
            if (relu) v = v > 0.f ? v : 0.f;
            C[(size_t)(rowD + r) * N + col] = f2bf(v);
        }
    }
}

// ---------------------------------------------------------------------------
// LDS-staged bf16 MFMA GEMM (m97 structure: 128x128 tile, BK=32,
// global_load_lds width 16, 2 barriers/K-step). K multiple of 32,
// M and N multiples of 128. grid = (N/128, M/128).
// C[M,N] = act(A[M,K] @ Bw[N,K]^T + bias), bf16 out, row stride ldc.
// Split-output mode (C2 != null): global cols >= 1024 go to C2 at col-1024.
// ---------------------------------------------------------------------------
__global__ __launch_bounds__(256) void k_gemm_t(
    const unsigned short* __restrict__ A, const unsigned short* __restrict__ Bw,
    const float* __restrict__ bias,
    unsigned short* __restrict__ C, unsigned short* __restrict__ C2,
    int N, int K, int ldc, int relu)
{
    __shared__ unsigned short lA[128 * 32];
    __shared__ unsigned short lB[128 * 32];
    int tid  = threadIdx.x;
    int lane = tid & 63;
    int wave = tid >> 6;
    int l16  = lane & 15, quad = lane >> 4;
    int wm = wave >> 1, wn = wave & 1;
    size_t mBase = (size_t)blockIdx.y * 128;
    size_t nBase = (size_t)blockIdx.x * 128;

    int c0 = tid, c1 = tid + 256;
    const unsigned short* sA0 = A  + (mBase + (c0 >> 2)) * K + (c0 & 3) * 8;
    const unsigned short* sA1 = A  + (mBase + (c1 >> 2)) * K + (c1 & 3) * 8;
    const unsigned short* sB0 = Bw + (nBase + (c0 >> 2)) * K + (c0 & 3) * 8;
    const unsigned short* sB1 = Bw + (nBase + (c1 >> 2)) * K + (c1 & 3) * 8;
    unsigned short* dA0 = lA + c0 * 8;
    unsigned short* dA1 = lA + c1 * 8;
    unsigned short* dB0 = lB + c0 * 8;
    unsigned short* dB1 = lB + c1 * 8;

    f32x4 acc[4][4];
    #pragma unroll
    for (int i = 0; i < 4; ++i)
        #pragma unroll
        for (int j = 0; j < 4; ++j) acc[i][j] = (f32x4){0.f, 0.f, 0.f, 0.f};

    const unsigned short* la = lA + (wm * 64 + l16) * 32 + quad * 8;
    const unsigned short* lb = lB + (wn * 64 + l16) * 32 + quad * 8;

    for (int k0 = 0; k0 < K; k0 += 32) {
        gld16(sA0 + k0, dA0);
        gld16(sA1 + k0, dA1);
        gld16(sB0 + k0, dB0);
        gld16(sB1 + k0, dB1);
        __syncthreads();                 // vmcnt(0) drain + barrier: tile ready
        short8 af[4], bf[4];
        #pragma unroll
        for (int i = 0; i < 4; ++i) {
            af[i] = *(const short8*)(const void*)(la + i * 16 * 32);
            bf[i] = *(const short8*)(const void*)(lb + i * 16 * 32);
        }
        #pragma unroll
        for (int i = 0; i < 4; ++i)
            #pragma unroll
            for (int j = 0; j < 4; ++j)
                acc[i][j] = __builtin_amdgcn_mfma_f32_16x16x32_bf16(af[i], bf[j], acc[i][j], 0, 0, 0);
        __syncthreads();                 // frags consumed before next overwrite
    }

    #pragma unroll
    for (int j = 0; j < 4; ++j) {
        int colg = (int)nBase + wn * 64 + j * 16 + l16;
        float bsum = bias[colg];
        unsigned short* dst = C;
        int cg = colg;
        if (C2 && colg >= 1024) { dst = C2; cg = colg - 1024; }
        #pragma unroll
        for (int i = 0; i < 4; ++i) {
            int row = (int)mBase + wm * 64 + i * 16 + quad * 4;
            #pragma unroll
            for (int r = 0; r < 4; ++r) {
                float v = acc[i][j][r] + bsum;
                if (relu) v = v > 0.f ? v : 0.f;
                dst[(size_t)(row + r) * ldc + cg] = f2bf(v);
            }
        }
    }
}

// ---------------------------------------------------------------------------
// delta features + batch reorder (unchanged)
// ---------------------------------------------------------------------------
__global__ void k_deltas(const unsigned short* __restrict__ hbuf, const int* __restrict__ order,
                         unsigned short* __restrict__ feat)
{
    int bt = blockIdx.x;        // bs*1024 + t
    int c  = threadIdx.x;       // 0..255
    int bs = bt >> 10, t = bt & 1023;
    int b  = order[bs];
    const unsigned short* hb = hbuf + (size_t)b * T_SZ * H3 + c;

    float hv[9];
    #pragma unroll
    for (int d = -4; d <= 4; ++d) {
        int tt = t + d;
        tt = tt < 0 ? 0 : (tt > T_SZ - 1 ? T_SZ - 1 : tt);
        hv[d + 4] = bf2f(hb[(size_t)tt * H3]);
    }
    float d1v[5];
    #pragma unroll
    for (int s = -2; s <= 2; ++s) {
        d1v[s + 2] = (hv[s + 5] - hv[s + 3]) * 0.5f + (hv[s + 6] - hv[s + 2]) * 0.25f;
    }
    int sp1 = (t + 1 > T_SZ - 1 ? T_SZ - 1 : t + 1) - t;
    int sm1 = (t - 1 < 0 ? 0 : t - 1) - t;
    int sp2 = (t + 2 > T_SZ - 1 ? T_SZ - 1 : t + 2) - t;
    int sm2 = (t - 2 < 0 ? 0 : t - 2) - t;
    float d2 = (d1v[2 + sp1] - d1v[2 + sm1]) * 0.5f + (d1v[2 + sp2] - d1v[2 + sm2]) * 0.25f;

    size_t fb = (size_t)bt * FEAT;
    feat[fb + c]       = hb[(size_t)t * H3];
    feat[fb + 256 + c] = f2bf(d1v[2]);
    feat[fb + 512 + c] = f2bf(d2);
}

// ---------------------------------------------------------------------------
// fp8 MX-MFMA LSTM recurrence v11: grid (rq 0..7, dir 0..1) = 16 blocks,
// 1024 threads (16 waves), one col/lane. Changes vs v10 (which regressed
// 824->849: the conflict-free layout's 4 separate uint4 reads + register
// packing cost more than the hidden bank conflicts it removed):
//  - REVERT to v9 32B-contiguous hA chunks: a0/a1 load as direct *(v8i*)
//    (2 clean ds_read_b128 each, no packing movs). Bank conflicts return
//    (~3.6M) but are measured-hidden.
//  - no setprio.
//  - gate prefetch + out store are pure POINTER WALKS (+-2048B / +-512
//    floats per step); the per-step clamp goes away. Out-of-range rows
//    (backward tail s >= elen-1, forward s+1 = maxlen) stay inside the
//    workspace / hbuf and their values are never consumed.
//  - acc C-operand: only element 0 is written per step (the gate input);
//    elements 1..3 correspond to zero A-rows, so mfma leaves them at their
//    initial value forever -- saves 12 v_movs/wave/step.
// ---------------------------------------------------------------------------
__global__ __launch_bounds__(1024, 4) void k_lstm_fp8(
    const unsigned short* __restrict__ g3f, const unsigned short* __restrict__ g3b,
    const unsigned char* __restrict__ wfrag8,
    const float* __restrict__ h0, const float* __restrict__ c0,
    const int* __restrict__ lens_sorted, float* __restrict__ out)
{
    int rq = blockIdx.x, dir = blockIdx.y;
    const unsigned short* g3 = (dir ? g3b : g3f) + (size_t)rq * 4194304;
    const unsigned char* wsrc = wfrag8 + (size_t)dir * 262144;

    __shared__ __align__(16) unsigned char hA[2][4096];

    int tid = threadIdx.x;
    int w = tid >> 6, lane = tid & 63;
    int l16 = lane & 15, quad = lane >> 4;

    // Whh fragments for this wave's 16 columns: regB[gb][kc], nt = gb*16 + w
    v8i regB[4][2];
    #pragma unroll
    for (int gb = 0; gb < 4; ++gb)
        #pragma unroll
        for (int kc = 0; kc < 2; ++kc) {
            int nt = gb * 16 + w;
            regB[gb][kc] = *(const v8i*)(const void*)
                (wsrc + ((size_t)((nt * 2 + kc) * 64 + lane)) * 32);
        }

    // zero both hA buffers (m-rows != 4b stay zero forever; fp8 0x00 == 0.0)
    for (int i = tid; i < 2048; i += 1024) ((unsigned int*)(void*)hA)[i] = 0;
    __syncthreads();
    // h0 -> hA[0] at m-row 4b: byte(m,k) at (k>>7)*2048 + (((k>>5)&3)*16+m)*32 + (k&31)
    {
        int b = tid >> 8, c = tid & 255;
        float hv = h0[(size_t)dir * B_SZ * HH + (size_t)(rq * 4 + b) * HH + c];
        hA[0][(c >> 7) * 2048 + (((c >> 5) & 3) * 16 + 4 * b) * 32 + (c & 31)] =
            (unsigned char)(__builtin_amdgcn_cvt_pk_fp8_f32(hv, hv, 0, false) & 0xff);
    }

    int grow = rq * 4 + quad;            // this lane's batch row (batch = quad)
    int elen = lens_sorted[grow];
    int maxlen = lens_sorted[rq * 4];    // sorted desc -> first of quad is max
    int col = w * 16 + l16;              // this lane's single h column
    float c2 = c0[(size_t)dir * B_SZ * HH + (size_t)grow * HH + col];
    // LDS write offset for this lane's fp8 h byte at m-row 4*quad
    int woff = (col >> 7) * 2048 + (((col >> 5) & 3) * 16 + 4 * quad) * 32 + (col & 31);

    // gate-row / out-row pointer walks (no per-step clamp; see header comment)
    int tr0 = dir ? (elen - 1) : 0;
    int gstep = dir ? -1024 : 1024;      // shorts per step
    int ostep = dir ? -512 : 512;        // floats per step
    const unsigned short* gp = g3 + ((size_t)quad << 20) + col + (size_t)tr0 * 1024;
    float* op = out + (size_t)grow * T_SZ * 512 + dir * HH + col + (size_t)tr0 * 512;

    // prefetch step-0 gate inputs (4 ushorts: one per gate, 512B apart)
    unsigned short gI = gp[0], gF = gp[256], gG = gp[512], gO = gp[768];
    gp += gstep;

    // acc elements 1..3 ride as constants (their A-rows are zero)
    f32x4 acc[4];
    #pragma unroll
    for (int gb = 0; gb < 4; ++gb) acc[gb] = (f32x4){0.f, 0.f, 0.f, 0.f};
    __syncthreads();

    for (int s = 0; s < maxlen; ++s) {
        // A-fragments FIRST: h(s-1), 32B per K-chunk per lane, contiguous
        const unsigned char* Ab = hA[s & 1];
        v8i a0 = *(const v8i*)(const void*)(Ab + lane * 32);
        v8i a1 = *(const v8i*)(const void*)(Ab + 2048 + lane * 32);

        // prefetch NEXT step's gates (pure pointer walk; lands during MFMAs)
        unsigned short nI = gp[0], nF = gp[256], nG = gp[512], nO = gp[768];
        gp += gstep;

        // gate input enters as C-operand element 0 (m-row 4*quad = batch)
        acc[0][0] = bf2f(gI);
        acc[1][0] = bf2f(gF);
        acc[2][0] = bf2f(gG);
        acc[3][0] = bf2f(gO);
        #pragma unroll
        for (int gb = 0; gb < 4; ++gb)
            acc[gb] = __builtin_amdgcn_mfma_scale_f32_16x16x128_f8f6f4(
                a0, regB[gb][0], acc[gb], 0, 0, 0, 0x7F7F7F7F, 0, 0x7F7F7F7F);
        #pragma unroll
        for (int gb = 0; gb < 4; ++gb)   // o gate (gb=3) last
            acc[gb] = __builtin_amdgcn_mfma_scale_f32_16x16x128_f8f6f4(
                a1, regB[gb][1], acc[gb], 0, 0, 0, 0x7F7F7F7F, 0, 0x7F7F7F7F);

        // epilogue: ONE h value per lane
        c2 = sigm(acc[1][0]) * c2 + sigm(acc[0][0]) * tanh_f(acc[2][0]);
        float tc = tanh_f(c2);
        float hv = sigm(acc[3][0]) * tc;

        hA[(s + 1) & 1][woff] =
            (unsigned char)(__builtin_amdgcn_cvt_pk_fp8_f32(hv, hv, 0, false) & 0xff);
        if (s < elen) *op = hv;
        op += ostep;
        gI = nI; gF = nF; gG = nG; gO = nO;
        // raw barrier: only the LDS h-write must drain; the out-store and
        // next-step gate loads stay in flight across the barrier.
        asm volatile("s_waitcnt lgkmcnt(0)" ::: "memory");
        __builtin_amdgcn_s_barrier();
    }
}

// ---------------------------------------------------------------------------
// Workspace layout (bytes). gates_f overlaps dead a0/a1 regions.
// ---------------------------------------------------------------------------
#define OFF_XBF    ((size_t)0)
#define OFF_A0     ((size_t)5242880)
#define OFF_A1     ((size_t)38797312)
#define OFF_HBUF   ((size_t)72351744)
#define OFF_FEAT   ((size_t)89128960)
#define OFF_GF     OFF_A0                  /* 67,108,864 B over a0+a1 (dead) */
#define OFF_GB     ((size_t)139460608)
#define OFF_W0     ((size_t)206569472)
#define OFF_W1     ((size_t)206651392)
#define OFF_W2     ((size_t)207175680)
#define OFF_WIHF   ((size_t)207437824)
#define OFF_WIHB   ((size_t)209010688)     /* contiguous after WIHF (merged B) */
#define OFF_WFRAG  ((size_t)210583552)     /* 524288 B: fp8 Whh fragments f+b */
#define OFF_BSUM   ((size_t)211107840)     /* float[2048] gate bias sums */
#define OFF_ORDER  ((size_t)212680704)
#define OFF_LENS   ((size_t)212680832)

extern "C" void kernel_launch(void* const* d_in, const int* in_sizes, int n_in,
                              void* d_out, int out_size, void* d_ws, size_t ws_size,
                              hipStream_t stream)
{
    const float* x    = (const float*)d_in[0];
    const int*   xlen = (const int*)d_in[1];
    const float* eW0  = (const float*)d_in[2];
    const float* eb0  = (const float*)d_in[3];
    const float* eW1  = (const float*)d_in[4];
    const float* eb1  = (const float*)d_in[5];
    const float* eW2  = (const float*)d_in[6];
    const float* eb2  = (const float*)d_in[7];
    const float* Wihf = (const float*)d_in[8];
    const float* Whhf = (const float*)d_in[9];
    const float* bihf = (const float*)d_in[10];
    const float* bhhf = (const float*)d_in[11];
    const float* Wihb = (const float*)d_in[12];
    const float* Whhb = (const float*)d_in[13];
    const float* bihb = (const float*)d_in[14];
    const float* bhhb = (const float*)d_in[15];
    const float* h0   = (const float*)d_in[16];
    const float* c0   = (const float*)d_in[17];
    float* out = (float*)d_out;

    char* ws = (char*)d_ws;
    unsigned short* xbf    = (unsigned short*)(ws + OFF_XBF);
    unsigned short* a0     = (unsigned short*)(ws + OFF_A0);
    unsigned short* a1     = (unsigned short*)(ws + OFF_A1);
    unsigned short* hbuf   = (unsigned short*)(ws + OFF_HBUF);
    unsigned short* feat   = (unsigned short*)(ws + OFF_FEAT);
    unsigned short* gatesF = (unsigned short*)(ws + OFF_GF);
    unsigned short* gatesB = (unsigned short*)(ws + OFF_GB);
    unsigned short* w0     = (unsigned short*)(ws + OFF_W0);
    unsigned short* w1     = (unsigned short*)(ws + OFF_W1);
    unsigned short* w2     = (unsigned short*)(ws + OFF_W2);
    unsigned short* wihf   = (unsigned short*)(ws + OFF_WIHF);
    unsigned short* wihb   = (unsigned short*)(ws + OFF_WIHB);
    unsigned char*  wfrag8 = (unsigned char*)(ws + OFF_WFRAG);
    float* bsum            = (float*)(ws + OFF_BSUM);
    int* order             = (int*)(ws + OFF_ORDER);
    int* lens_sorted       = (int*)(ws + OFF_LENS);

    // prep: conversions + bias sums + argsort + Whh fp8 fragments, one launch
    k_cvtw<<<1024, 256, 0, stream>>>(x, xbf, eW0, w0, eW1, w1, eW2, w2,
                                     Wihf, wihf, Wihb, wihb,
                                     bihf, bhhf, bihb, bhhb, bsum,
                                     xlen, order, lens_sorted,
                                     out + (size_t)B_SZ * T_SZ * 512,
                                     Whhf, Whhb, wfrag8);
    k_ztail<<<dim3(T_SZ, B_SZ), 128, 0, stream>>>(lens_sorted, out);

    // encoder: 80 -> 512 -> 512 -> 256, ReLU each layer (row-major stores)
    k_gemm<<<dim3(1024, 4), 256, 0, stream>>>(xbf, w0, eb0, a0, 32768, 512, 80, 1);
    k_gemm_t<<<dim3(4, 256), 256, 0, stream>>>(a0, w1, eb1, a1,   nullptr, 512, 512, 512, 1);
    k_gemm_t<<<dim3(2, 256), 256, 0, stream>>>(a1, w2, eb2, hbuf, nullptr, 256, 512, 256, 1);

    // delta features + sort reorder -> feat[bs,t,768]
    k_deltas<<<32768, 256, 0, stream>>>(hbuf, order, feat);

    // gate inputs, BOTH directions in one GEMM: B = [wihf; wihb] (adjacent in
    // ws), cols < 1024 -> gatesF, >= 1024 -> gatesB (each [32768][1024]).
    k_gemm_t<<<dim3(16, 256), 256, 0, stream>>>(feat, wihf, bsum, gatesF, gatesB,
                                                2048, 768, 1024, 0);

    // fp8 MX recurrence: 16 independent blocks (2 dirs x 8 batch quads), no sync
    k_lstm_fp8<<<dim3(8, 2), 1024, 0, stream>>>(gatesF, gatesB, wfrag8, h0, c0,
                                                lens_sorted, out);
}

// Round 8
// 1097.743 us; speedup vs baseline: 1.1276x; 1.0305x over previous
//
#include <hip/hip_runtime.h>
#include <cstdint>
#include <cstddef>

// ---------------------------------------------------------------------------
// Problem constants
// ---------------------------------------------------------------------------
#define B_SZ 32
#define T_SZ 1024
#define DIN  80
#define H3   256   // encoder output dim
#define FEAT 768   // 3 * H3
#define G4   1024  // 4 * H (LSTM gates)
#define HH   256   // LSTM hidden

typedef __attribute__((ext_vector_type(8))) short short8;   // 8 x bf16 (4 VGPRs)
typedef __attribute__((ext_vector_type(4))) float f32x4;    // MFMA accumulator
typedef __attribute__((ext_vector_type(8))) int v8i;        // 32B fp8 fragment

__device__ inline float bf2f(unsigned short u) {
    return __uint_as_float(((unsigned int)u) << 16);
}
__device__ inline unsigned short f2bf(float f) {
    unsigned int u = __float_as_uint(f);
    u += 0x7fffu + ((u >> 16) & 1u);   // RNE
    return (unsigned short)(u >> 16);
}
// fast sigmoid/tanh: v_exp (exp2) + v_rcp
#define LOG2E 1.4426950408889634f
__device__ inline float sigm(float x) {
    return __builtin_amdgcn_rcpf(1.f + __builtin_amdgcn_exp2f(x * -LOG2E));
}
__device__ inline float tanh_f(float x) {
    return fmaf(2.f, __builtin_amdgcn_rcpf(1.f + __builtin_amdgcn_exp2f(x * (-2.f * LOG2E))), -1.f);
}

// async global->LDS, 16B per lane (dest must be linear: base + lane*16)
__device__ inline void gld16(const void* g, void* l) {
    __builtin_amdgcn_global_load_lds(
        (const __attribute__((address_space(1))) unsigned int*)g,
        (__attribute__((address_space(3))) unsigned int*)l, 16, 0, 0);
}

// ---------------------------------------------------------------------------
// fp32 -> bf16 conversion, float4-vectorized (n4 = n/4)
// ---------------------------------------------------------------------------
__device__ inline void cvt_seg(const float* __restrict__ s, unsigned short* __restrict__ d,
                               int n4, int i, int stride) {
    for (int k = i; k < n4; k += stride) {
        float4 f = ((const float4*)(const void*)s)[k];
        ushort4 u;
        u.x = f2bf(f.x); u.y = f2bf(f.y); u.z = f2bf(f.z); u.w = f2bf(f.w);
        ((ushort4*)(void*)d)[k] = u;
    }
}

// x + five weight matrices + gate-bias sums + argsort + Whh fp8 fragments,
// all in ONE launch (k_wfrag8 fused in: independent of the other segments).
__global__ void k_cvtw(const float* __restrict__ x,  unsigned short* __restrict__ xbf,
                       const float* __restrict__ s0, unsigned short* __restrict__ d0,
                       const float* __restrict__ s1, unsigned short* __restrict__ d1,
                       const float* __restrict__ s2, unsigned short* __restrict__ d2,
                       const float* __restrict__ s3, unsigned short* __restrict__ d3,
                       const float* __restrict__ s4, unsigned short* __restrict__ d4,
                       const float* __restrict__ bihf, const float* __restrict__ bhhf,
                       const float* __restrict__ bihb, const float* __restrict__ bhhb,
                       float* __restrict__ bsum,
                       const int* __restrict__ lens, int* __restrict__ order,
                       int* __restrict__ lens_sorted, float* __restrict__ out_order,
                       const float* __restrict__ Whhf, const float* __restrict__ Whhb,
                       unsigned char* __restrict__ wfrag) {
    int i = blockIdx.x * 256 + threadIdx.x;
    int stride = gridDim.x * 256;
    cvt_seg(x,  xbf, 655360, i, stride);  // 32*1024*80 / 4
    cvt_seg(s0, d0, 10240,  i, stride);   // 512*80
    cvt_seg(s1, d1, 65536,  i, stride);   // 512*512
    cvt_seg(s2, d2, 32768,  i, stride);   // 256*512
    cvt_seg(s3, d3, 196608, i, stride);   // 1024*768
    cvt_seg(s4, d4, 196608, i, stride);   // 1024*768
    if (i < 2048)
        bsum[i] = (i < 1024) ? (bihf[i] + bhhf[i]) : (bihb[i - 1024] + bhhb[i - 1024]);
    if (i < B_SZ) {   // stable argsort by descending length
        int lb = lens[i];
        int r = 0;
        for (int j = 0; j < B_SZ; ++j) {
            int lj = lens[j];
            if (lj > lb || (lj == lb && j < i)) ++r;
        }
        order[r] = i;
        lens_sorted[r] = lb;
        out_order[r] = (float)i;   // second tuple output, as float
    }
    // Whh -> fp8 MFMA B-fragments (identity n mapping, one col per lane):
    // slot (nt,kc): n = nt*16 + (lane&15), k = kc*128 + (lane>>4)*32 + j.
    // byte addr = ((nt*2+kc)*64 + lane)*32, one thread per 16B half.
    if (i < 32768) {
        int t = i;
        int dir = t >> 14;
        t &= 16383;
        const float* Whh = dir ? Whhb : Whhf;
        unsigned char* d = wfrag + (size_t)dir * 262144;
        int lane = t & 63, hf = (t >> 6) & 1, kc = (t >> 7) & 1, nt = t >> 8;
        int n = nt * 16 + (lane & 15);
        int k0 = kc * 128 + (lane >> 4) * 32 + hf * 16;
        const float* p = Whh + (size_t)n * 256 + k0;
        unsigned int o[4];
        #pragma unroll
        for (int q = 0; q < 4; ++q) {
            float4 f = *(const float4*)(const void*)(p + 4 * q);
            o[q] = (__builtin_amdgcn_cvt_pk_fp8_f32(f.x, f.y, 0, false) & 0xffff)
                 | (__builtin_amdgcn_cvt_pk_fp8_f32(f.z, f.w, 0, false) << 16);
        }
        int slot = (nt * 2 + kc) * 64 + lane;
        *(uint4*)(void*)(d + (size_t)slot * 32 + hf * 16) = make_uint4(o[0], o[1], o[2], o[3]);
    }
}

// zero the padded tail: out[bs, t, 0:512] = 0 for t >= len[bs]
__global__ void k_ztail(const int* __restrict__ lens_sorted, float* __restrict__ out) {
    int t = blockIdx.x, bs = blockIdx.y;
    if (t < lens_sorted[bs]) return;
    float4* p = (float4*)(out + ((size_t)bs * T_SZ + t) * 512);
    p[threadIdx.x] = make_float4(0.f, 0.f, 0.f, 0.f);   // 128 threads x 16B
}

// ---------------------------------------------------------------------------
// direct bf16 MFMA GEMM (kept only for K=80 encoder layer 0)
// Block tile 32(M) x 128(N), 4 waves (2x2), each wave 16x64 via 4 accums.
// ---------------------------------------------------------------------------
__global__ __launch_bounds__(256) void k_gemm(
    const unsigned short* __restrict__ A, const unsigned short* __restrict__ Bw,
    const float* __restrict__ bias,
    unsigned short* __restrict__ C, int M, int N, int K, int relu)
{
    int tid  = threadIdx.x;
    int lane = tid & 63;
    int wave = tid >> 6;
    int waveM = wave >> 1, waveN = wave & 1;
    int l16  = lane & 15;
    int quad = lane >> 4;
    int mBase = blockIdx.x * 32 + waveM * 16;
    int nBase = blockIdx.y * 128 + waveN * 64;

    const unsigned short* pA  = A  + (size_t)(mBase + l16) * K + quad * 8;
    const unsigned short* pB0 = Bw + (size_t)(nBase +  0 + l16) * K + quad * 8;
    const unsigned short* pB1 = Bw + (size_t)(nBase + 16 + l16) * K + quad * 8;
    const unsigned short* pB2 = Bw + (size_t)(nBase + 32 + l16) * K + quad * 8;
    const unsigned short* pB3 = Bw + (size_t)(nBase + 48 + l16) * K + quad * 8;

    const short8 z8 = {0, 0, 0, 0, 0, 0, 0, 0};
    f32x4 acc0 = {0.f, 0.f, 0.f, 0.f};
    f32x4 acc1 = acc0, acc2 = acc0, acc3 = acc0;

    for (int k0 = 0; k0 < K; k0 += 32) {
        bool ok = (k0 + quad * 8) < K;
        short8 av  = ok ? *(const short8*)(const void*)(pA  + k0) : z8;
        short8 bv0 = ok ? *(const short8*)(const void*)(pB0 + k0) : z8;
        short8 bv1 = ok ? *(const short8*)(const void*)(pB1 + k0) : z8;
        short8 bv2 = ok ? *(const short8*)(const void*)(pB2 + k0) : z8;
        short8 bv3 = ok ? *(const short8*)(const void*)(pB3 + k0) : z8;
        acc0 = __builtin_amdgcn_mfma_f32_16x16x32_bf16(av, bv0, acc0, 0, 0, 0);
        acc1 = __builtin_amdgcn_mfma_f32_16x16x32_bf16(av, bv1, acc1, 0, 0, 0);
        acc2 = __builtin_amdgcn_mfma_f32_16x16x32_bf16(av, bv2, acc2, 0, 0, 0);
        acc3 = __builtin_amdgcn_mfma_f32_16x16x32_bf16(av, bv3, acc3, 0, 0, 0);
    }

    int rowD = mBase + quad * 4;
    #pragma unroll
    for (int nt = 0; nt < 4; ++nt) {
        int col = nBase + nt * 16 + l16;
        float bsum = bias ? bias[col] : 0.f;
        f32x4 a = (nt == 0) ? acc0 : (nt == 1) ? acc1 : (nt == 2) ? acc2 : acc3;
        #pragma unroll
        for (int r = 0; r < 4; ++r) {
            float v = a[r] + bsum;
            if (relu) v = v > 0.f ? v : 0.f;
            C[(size_t)(rowD + r) * N + col] = f2bf(v);
        }
    }
}

// ---------------------------------------------------------------------------
// LDS-staged bf16 MFMA GEMM v2: 128x128 tile, BK=32, global_load_lds w16,
// DOUBLE-BUFFERED (T3-minimal 2-phase): STAGE(t+1) issues BEFORE compute(t),
// one __syncthreads per K-step drains it AFTER the MFMAs -- the loads get
// the whole compute phase to land instead of a serial vmcnt(0) stall.
// K multiple of 32, M and N multiples of 128. grid = (N/128, M/128).
// C[M,N] = act(A[M,K] @ Bw[N,K]^T + bias), bf16 out, row stride ldc.
// Split-output mode (C2 != null): global cols >= 1024 go to C2 at col-1024.
// ---------------------------------------------------------------------------
__global__ __launch_bounds__(256) void k_gemm_t(
    const unsigned short* __restrict__ A, const unsigned short* __restrict__ Bw,
    const float* __restrict__ bias,
    unsigned short* __restrict__ C, unsigned short* __restrict__ C2,
    int N, int K, int ldc, int relu)
{
    __shared__ unsigned short lA[2][128 * 32];
    __shared__ unsigned short lB[2][128 * 32];
    int tid  = threadIdx.x;
    int lane = tid & 63;
    int wave = tid >> 6;
    int l16  = lane & 15, quad = lane >> 4;
    int wm = wave >> 1, wn = wave & 1;
    size_t mBase = (size_t)blockIdx.y * 128;
    size_t nBase = (size_t)blockIdx.x * 128;

    int c0 = tid, c1 = tid + 256;
    const unsigned short* sA0 = A  + (mBase + (c0 >> 2)) * K + (c0 & 3) * 8;
    const unsigned short* sA1 = A  + (mBase + (c1 >> 2)) * K + (c1 & 3) * 8;
    const unsigned short* sB0 = Bw + (nBase + (c0 >> 2)) * K + (c0 & 3) * 8;
    const unsigned short* sB1 = Bw + (nBase + (c1 >> 2)) * K + (c1 & 3) * 8;

    f32x4 acc[4][4];
    #pragma unroll
    for (int i = 0; i < 4; ++i)
        #pragma unroll
        for (int j = 0; j < 4; ++j) acc[i][j] = (f32x4){0.f, 0.f, 0.f, 0.f};

    int roffA = (wm * 64 + l16) * 32 + quad * 8;
    int roffB = (wn * 64 + l16) * 32 + quad * 8;

    auto STAGE = [&](int b, int k0) {
        gld16(sA0 + k0, lA[b] + c0 * 8);
        gld16(sA1 + k0, lA[b] + c1 * 8);
        gld16(sB0 + k0, lB[b] + c0 * 8);
        gld16(sB1 + k0, lB[b] + c1 * 8);
    };

    STAGE(0, 0);
    __syncthreads();                     // prologue drain: buffer 0 ready
    int cur = 0;
    for (int k0 = 0; k0 < K; k0 += 32) {
        if (k0 + 32 < K) STAGE(cur ^ 1, k0 + 32);   // prefetch next tile
        const unsigned short* la = lA[cur] + roffA;
        const unsigned short* lb = lB[cur] + roffB;
        short8 af[4], bf[4];
        #pragma unroll
        for (int i = 0; i < 4; ++i) {
            af[i] = *(const short8*)(const void*)(la + i * 16 * 32);
            bf[i] = *(const short8*)(const void*)(lb + i * 16 * 32);
        }
        #pragma unroll
        for (int i = 0; i < 4; ++i)
            #pragma unroll
            for (int j = 0; j < 4; ++j)
                acc[i][j] = __builtin_amdgcn_mfma_f32_16x16x32_bf16(af[i], bf[j], acc[i][j], 0, 0, 0);
        __syncthreads();                 // drains prefetch (hidden under MFMAs)
        cur ^= 1;
    }

    #pragma unroll
    for (int j = 0; j < 4; ++j) {
        int colg = (int)nBase + wn * 64 + j * 16 + l16;
        float bsum = bias[colg];
        unsigned short* dst = C;
        int cg = colg;
        if (C2 && colg >= 1024) { dst = C2; cg = colg - 1024; }
        #pragma unroll
        for (int i = 0; i < 4; ++i) {
            int row = (int)mBase + wm * 64 + i * 16 + quad * 4;
            #pragma unroll
            for (int r = 0; r < 4; ++r) {
                float v = acc[i][j][r] + bsum;
                if (relu) v = v > 0.f ? v : 0.f;
                dst[(size_t)(row + r) * ldc + cg] = f2bf(v);
            }
        }
    }
}

// ---------------------------------------------------------------------------
// delta features + batch reorder, 4 consecutive t per block: taps shared
// across rows (12 loads/thread instead of 36), 8192 blocks instead of 32768.
// ---------------------------------------------------------------------------
__global__ void k_deltas(const unsigned short* __restrict__ hbuf, const int* __restrict__ order,
                         unsigned short* __restrict__ feat)
{
    int blk = blockIdx.x;           // bs*256 + t-group
    int bs = blk >> 8, t0 = (blk & 255) << 2;
    int c  = threadIdx.x;           // 0..255
    int b  = order[bs];
    const unsigned short* hb = hbuf + (size_t)b * T_SZ * H3 + c;

    // 12 taps: positions t0-4 .. t0+7, edge-clamped
    unsigned short raw[12];
    float hv[12];
    #pragma unroll
    for (int d = 0; d < 12; ++d) {
        int tt = t0 - 4 + d;
        tt = tt < 0 ? 0 : (tt > T_SZ - 1 ? T_SZ - 1 : tt);
        raw[d] = hb[(size_t)tt * H3];
        hv[d] = bf2f(raw[d]);
    }
    // d1 at absolute positions u = t0-2 .. t0+5 (local j = u-(t0-2));
    // d1(u) uses taps clamp(u+-1), clamp(u+-2) == hv[j+3],hv[j+1],hv[j+4],hv[j]
    float d1v[8];
    #pragma unroll
    for (int j = 0; j < 8; ++j)
        d1v[j] = (hv[j + 3] - hv[j + 1]) * 0.5f + (hv[j + 4] - hv[j]) * 0.25f;

    #pragma unroll
    for (int r = 0; r < 4; ++r) {
        int t = t0 + r;
        int p1 = t + 1 > T_SZ - 1 ? T_SZ - 1 : t + 1;
        int m1 = t - 1 < 0 ? 0 : t - 1;
        int p2 = t + 2 > T_SZ - 1 ? T_SZ - 1 : t + 2;
        int m2 = t - 2 < 0 ? 0 : t - 2;
        float d2 = (d1v[p1 - t0 + 2] - d1v[m1 - t0 + 2]) * 0.5f
                 + (d1v[p2 - t0 + 2] - d1v[m2 - t0 + 2]) * 0.25f;
        size_t fb = ((size_t)(bs << 10) + t) * FEAT;
        feat[fb + c]       = raw[4 + r];
        feat[fb + 256 + c] = f2bf(d1v[r + 2]);
        feat[fb + 512 + c] = f2bf(d2);
    }
}

// ---------------------------------------------------------------------------
// fp8 MX-MFMA LSTM recurrence v11 (unchanged from R7 winner): 16 blocks,
// 1024 threads (16 waves), one col/lane, pointer-walk gates/out, gate input
// as MFMA C-operand element 0, raw lgkmcnt(0)+s_barrier per step.
// Step ~1733 cyc vs 1104 MFMA floor; residual is the lockstep-wave
// epilogue/barrier/ds_read window (structural -- see R6/R7 notes).
// ---------------------------------------------------------------------------
__global__ __launch_bounds__(1024, 4) void k_lstm_fp8(
    const unsigned short* __restrict__ g3f, const unsigned short* __restrict__ g3b,
    const unsigned char* __restrict__ wfrag8,
    const float* __restrict__ h0, const float* __restrict__ c0,
    const int* __restrict__ lens_sorted, float* __restrict__ out)
{
    int rq = blockIdx.x, dir = blockIdx.y;
    const unsigned short* g3 = (dir ? g3b : g3f) + (size_t)rq * 4194304;
    const unsigned char* wsrc = wfrag8 + (size_t)dir * 262144;

    __shared__ __align__(16) unsigned char hA[2][4096];

    int tid = threadIdx.x;
    int w = tid >> 6, lane = tid & 63;
    int l16 = lane & 15, quad = lane >> 4;

    // Whh fragments for this wave's 16 columns: regB[gb][kc], nt = gb*16 + w
    v8i regB[4][2];
    #pragma unroll
    for (int gb = 0; gb < 4; ++gb)
        #pragma unroll
        for (int kc = 0; kc < 2; ++kc) {
            int nt = gb * 16 + w;
            regB[gb][kc] = *(const v8i*)(const void*)
                (wsrc + ((size_t)((nt * 2 + kc) * 64 + lane)) * 32);
        }

    // zero both hA buffers (m-rows != 4b stay zero forever; fp8 0x00 == 0.0)
    for (int i = tid; i < 2048; i += 1024) ((unsigned int*)(void*)hA)[i] = 0;
    __syncthreads();
    // h0 -> hA[0] at m-row 4b: byte(m,k) at (k>>7)*2048 + (((k>>5)&3)*16+m)*32 + (k&31)
    {
        int b = tid >> 8, c = tid & 255;
        float hv = h0[(size_t)dir * B_SZ * HH + (size_t)(rq * 4 + b) * HH + c];
        hA[0][(c >> 7) * 2048 + (((c >> 5) & 3) * 16 + 4 * b) * 32 + (c & 31)] =
            (unsigned char)(__builtin_amdgcn_cvt_pk_fp8_f32(hv, hv, 0, false) & 0xff);
    }

    int grow = rq * 4 + quad;            // this lane's batch row (batch = quad)
    int elen = lens_sorted[grow];
    int maxlen = lens_sorted[rq * 4];    // sorted desc -> first of quad is max
    int col = w * 16 + l16;              // this lane's single h column
    float c2 = c0[(size_t)dir * B_SZ * HH + (size_t)grow * HH + col];
    // LDS write offset for this lane's fp8 h byte at m-row 4*quad
    int woff = (col >> 7) * 2048 + (((col >> 5) & 3) * 16 + 4 * quad) * 32 + (col & 31);

    // gate-row / out-row pointer walks (no per-step clamp; OOB rows stay
    // inside the workspace and their values are never consumed)
    int tr0 = dir ? (elen - 1) : 0;
    int gstep = dir ? -1024 : 1024;      // shorts per step
    int ostep = dir ? -512 : 512;        // floats per step
    const unsigned short* gp = g3 + ((size_t)quad << 20) + col + (size_t)tr0 * 1024;
    float* op = out + (size_t)grow * T_SZ * 512 + dir * HH + col + (size_t)tr0 * 512;

    // prefetch step-0 gate inputs (4 ushorts: one per gate, 512B apart)
    unsigned short gI = gp[0], gF = gp[256], gG = gp[512], gO = gp[768];
    gp += gstep;

    // acc elements 1..3 ride as constants (their A-rows are zero)
    f32x4 acc[4];
    #pragma unroll
    for (int gb = 0; gb < 4; ++gb) acc[gb] = (f32x4){0.f, 0.f, 0.f, 0.f};
    __syncthreads();

    for (int s = 0; s < maxlen; ++s) {
        // A-fragments FIRST: h(s-1), 32B per K-chunk per lane, contiguous
        const unsigned char* Ab = hA[s & 1];
        v8i a0 = *(const v8i*)(const void*)(Ab + lane * 32);
        v8i a1 = *(const v8i*)(const void*)(Ab + 2048 + lane * 32);

        // prefetch NEXT step's gates (pure pointer walk; lands during MFMAs)
        unsigned short nI = gp[0], nF = gp[256], nG = gp[512], nO = gp[768];
        gp += gstep;

        // gate input enters as C-operand element 0 (m-row 4*quad = batch)
        acc[0][0] = bf2f(gI);
        acc[1][0] = bf2f(gF);
        acc[2][0] = bf2f(gG);
        acc[3][0] = bf2f(gO);
        #pragma unroll
        for (int gb = 0; gb < 4; ++gb)
            acc[gb] = __builtin_amdgcn_mfma_scale_f32_16x16x128_f8f6f4(
                a0, regB[gb][0], acc[gb], 0, 0, 0, 0x7F7F7F7F, 0, 0x7F7F7F7F);
        #pragma unroll
        for (int gb = 0; gb < 4; ++gb)   // o gate (gb=3) last
            acc[gb] = __builtin_amdgcn_mfma_scale_f32_16x16x128_f8f6f4(
                a1, regB[gb][1], acc[gb], 0, 0, 0, 0x7F7F7F7F, 0, 0x7F7F7F7F);

        // epilogue: ONE h value per lane
        c2 = sigm(acc[1][0]) * c2 + sigm(acc[0][0]) * tanh_f(acc[2][0]);
        float tc = tanh_f(c2);
        float hv = sigm(acc[3][0]) * tc;

        hA[(s + 1) & 1][woff] =
            (unsigned char)(__builtin_amdgcn_cvt_pk_fp8_f32(hv, hv, 0, false) & 0xff);
        if (s < elen) *op = hv;
        op += ostep;
        gI = nI; gF = nF; gG = nG; gO = nO;
        // raw barrier: only the LDS h-write must drain; the out-store and
        // next-step gate loads stay in flight across the barrier.
        asm volatile("s_waitcnt lgkmcnt(0)" ::: "memory");
        __builtin_amdgcn_s_barrier();
    }
}

// ---------------------------------------------------------------------------
// Workspace layout (bytes). gates_f overlaps dead a0/a1 regions.
// ---------------------------------------------------------------------------
#define OFF_XBF    ((size_t)0)
#define OFF_A0     ((size_t)5242880)
#define OFF_A1     ((size_t)38797312)
#define OFF_HBUF   ((size_t)72351744)
#define OFF_FEAT   ((size_t)89128960)
#define OFF_GF     OFF_A0                  /* 67,108,864 B over a0+a1 (dead) */
#define OFF_GB     ((size_t)139460608)
#define OFF_W0     ((size_t)206569472)
#define OFF_W1     ((size_t)206651392)
#define OFF_W2     ((size_t)207175680)
#define OFF_WIHF   ((size_t)207437824)
#define OFF_WIHB   ((size_t)209010688)     /* contiguous after WIHF (merged B) */
#define OFF_WFRAG  ((size_t)210583552)     /* 524288 B: fp8 Whh fragments f+b */
#define OFF_BSUM   ((size_t)211107840)     /* float[2048] gate bias sums */
#define OFF_ORDER  ((size_t)212680704)
#define OFF_LENS   ((size_t)212680832)

extern "C" void kernel_launch(void* const* d_in, const int* in_sizes, int n_in,
                              void* d_out, int out_size, void* d_ws, size_t ws_size,
                              hipStream_t stream)
{
    const float* x    = (const float*)d_in[0];
    const int*   xlen = (const int*)d_in[1];
    const float* eW0  = (const float*)d_in[2];
    const float* eb0  = (const float*)d_in[3];
    const float* eW1  = (const float*)d_in[4];
    const float* eb1  = (const float*)d_in[5];
    const float* eW2  = (const float*)d_in[6];
    const float* eb2  = (const float*)d_in[7];
    const float* Wihf = (const float*)d_in[8];
    const float* Whhf = (const float*)d_in[9];
    const float* bihf = (const float*)d_in[10];
    const float* bhhf = (const float*)d_in[11];
    const float* Wihb = (const float*)d_in[12];
    const float* Whhb = (const float*)d_in[13];
    const float* bihb = (const float*)d_in[14];
    const float* bhhb = (const float*)d_in[15];
    const float* h0   = (const float*)d_in[16];
    const float* c0   = (const float*)d_in[17];
    float* out = (float*)d_out;

    char* ws = (char*)d_ws;
    unsigned short* xbf    = (unsigned short*)(ws + OFF_XBF);
    unsigned short* a0     = (unsigned short*)(ws + OFF_A0);
    unsigned short* a1     = (unsigned short*)(ws + OFF_A1);
    unsigned short* hbuf   = (unsigned short*)(ws + OFF_HBUF);
    unsigned short* feat   = (unsigned short*)(ws + OFF_FEAT);
    unsigned short* gatesF = (unsigned short*)(ws + OFF_GF);
    unsigned short* gatesB = (unsigned short*)(ws + OFF_GB);
    unsigned short* w0     = (unsigned short*)(ws + OFF_W0);
    unsigned short* w1     = (unsigned short*)(ws + OFF_W1);
    unsigned short* w2     = (unsigned short*)(ws + OFF_W2);
    unsigned short* wihf   = (unsigned short*)(ws + OFF_WIHF);
    unsigned short* wihb   = (unsigned short*)(ws + OFF_WIHB);
    unsigned char*  wfrag8 = (unsigned char*)(ws + OFF_WFRAG);
    float* bsum            = (float*)(ws + OFF_BSUM);
    int* order             = (int*)(ws + OFF_ORDER);
    int* lens_sorted       = (int*)(ws + OFF_LENS);

    // prep: conversions + bias sums + argsort + Whh fp8 fragments, one launch
    k_cvtw<<<1024, 256, 0, stream>>>(x, xbf, eW0, w0, eW1, w1, eW2, w2,
                                     Wihf, wihf, Wihb, wihb,
                                     bihf, bhhf, bihb, bhhb, bsum,
                                     xlen, order, lens_sorted,
                                     out + (size_t)B_SZ * T_SZ * 512,
                                     Whhf, Whhb, wfrag8);
    k_ztail<<<dim3(T_SZ, B_SZ), 128, 0, stream>>>(lens_sorted, out);

    // encoder: 80 -> 512 -> 512 -> 256, ReLU each layer (row-major stores)
    k_gemm<<<dim3(1024, 4), 256, 0, stream>>>(xbf, w0, eb0, a0, 32768, 512, 80, 1);
    k_gemm_t<<<dim3(4, 256), 256, 0, stream>>>(a0, w1, eb1, a1,   nullptr, 512, 512, 512, 1);
    k_gemm_t<<<dim3(2, 256), 256, 0, stream>>>(a1, w2, eb2, hbuf, nullptr, 256, 512, 256, 1);

    // delta features + sort reorder -> feat[bs,t,768] (4 t-rows per block)
    k_deltas<<<8192, 256, 0, stream>>>(hbuf, order, feat);

    // gate inputs, BOTH directions in one GEMM: B = [wihf; wihb] (adjacent in
    // ws), cols < 1024 -> gatesF, >= 1024 -> gatesB (each [32768][1024]).
    k_gemm_t<<<dim3(16, 256), 256, 0, stream>>>(feat, wihf, bsum, gatesF, gatesB,
                                                2048, 768, 1024, 0);

    // fp8 MX recurrence: 16 independent blocks (2 dirs x 8 batch quads), no sync
    k_lstm_fp8<<<dim3(8, 2), 1024, 0, stream>>>(gatesF, gatesB, wfrag8, h0, c0,
                                                lens_sorted, out);
}